// Round 9
// baseline (303.524 us; speedup 1.0000x reference)
//
#include <hip/hip_runtime.h>
#include <hip/hip_bf16.h>

#define DI __device__ __forceinline__
using u16 = unsigned short;
using u32 = unsigned int;

typedef short short8 __attribute__((ext_vector_type(8)));   // 8 bf16 (4 VGPRs)
typedef float f32x4 __attribute__((ext_vector_type(4)));

#define F4C(v, i) ((i) == 0 ? (v).x : (i) == 1 ? (v).y : (i) == 2 ? (v).z : (v).w)

DI float bflo(u32 u) { return __uint_as_float(u << 16); }
DI float bfhi(u32 u) { return __uint_as_float(u & 0xffff0000u); }
DI float bfel(uint2 u, int j) { u32 w = (j < 2) ? u.x : u.y; return (j & 1) ? bfhi(w) : bflo(w); }
DI u16 f2bf(float a) {
  u32 xu = __float_as_uint(a);
  return (u16)((xu + 0x7fffu + ((xu >> 16) & 1)) >> 16);
}
DI u32 pack_bf16x2(float a, float b) {
  u32 xu = __float_as_uint(a), yu = __float_as_uint(b);
  xu = (xu + 0x7fffu + ((xu >> 16) & 1)) >> 16;
  yu = (yu + 0x7fffu + ((yu >> 16) & 1)) >> 16;
  return (xu & 0xffffu) | (yu << 16);
}

// ---------------- workspace layout (float units) ----------------
static constexpr size_t OFF_REGB = 0;
static constexpr size_t OFF_REGA = 16777216;
static constexpr size_t OFF_WT0  = 33554432;
static constexpr size_t OFF_WT1  = OFF_WT0 + 1179648;
static constexpr size_t OFF_WT2  = OFF_WT1 + 294912;
static constexpr size_t OFF_WTF  = OFF_WT2 + 73728;
static constexpr size_t OFF_ST   = 35200000;
static constexpr size_t O_SC0 = OFF_ST,          O_SH0 = OFF_ST + 262144;
static constexpr size_t O_SC1 = OFF_ST + 524288, O_SH1 = OFF_ST + 655360;
static constexpr size_t O_SC2 = OFF_ST + 786432, O_SH2 = OFF_ST + 851968;
static constexpr size_t O_SC3 = OFF_ST + 917504, O_SH3 = OFF_ST + 950272;

// ---------------- all weight pre-transposes in one launch ----------------
__global__ __launch_bounds__(256)
void wtrans_all(const float* __restrict__ dw0, const float* __restrict__ dw1,
                const float* __restrict__ dw2, const float* __restrict__ fcw,
                u16* __restrict__ wt0, u16* __restrict__ wt1,
                u16* __restrict__ wt2, u16* __restrict__ wtf)
{
  int id = blockIdx.x * 256 + threadIdx.x;
  if (id < 131072) {                       // dw0: CO=256, CI=512
    int m = id >> 9, c = id & 511;
    const float* src = dw0 + ((size_t)m * 512 + c) * 9;
#pragma unroll
    for (int tap = 0; tap < 9; ++tap)
      wt0[((size_t)tap * 256 + m) * 512 + c] = f2bf(src[tap]);
  } else if (id < 163840) {                // dw1: CO=128, CI=256
    int j = id - 131072;
    int m = j >> 8, c = j & 255;
    const float* src = dw1 + ((size_t)m * 256 + c) * 9;
#pragma unroll
    for (int tap = 0; tap < 9; ++tap)
      wt1[((size_t)tap * 128 + m) * 256 + c] = f2bf(src[tap]);
  } else if (id < 172032) {                // dw2: CO=64, CI=128
    int j = id - 163840;
    int m = j >> 7, c = j & 127;
    const float* src = dw2 + ((size_t)m * 128 + c) * 9;
#pragma unroll
    for (int tap = 0; tap < 9; ++tap)
      wt2[((size_t)tap * 64 + m) * 128 + c] = f2bf(src[tap]);
  } else {                                 // fc: wtf[d][c]
    int j = id - 172032;
    int d = j >> 8, c = j & 255;
    wtf[j] = f2bf(fcw[c * 512 + d]);
  }
}

// ---------------- fc1 via MFMA + fused GN0 stats ----------------
DI void fc_stage_A(const float* __restrict__ feat, int b, u16* Ab, int t)
{
#pragma unroll
  for (int it = 0; it < 2; ++it) {
    int idx = t + it * 256;
    int cp = idx >> 2, hw4 = idx & 3;
    int c = cp * 2;
    const float* xp = feat + ((size_t)b * 256 + c) * 16 + hw4 * 4;
    float4 v0 = *(const float4*)xp;
    float4 v1 = *(const float4*)(xp + 16);
    int c64 = c >> 6, jb = (c & 63) >> 3;
#pragma unroll
    for (int j = 0; j < 4; ++j) {
      int hw = hw4 * 4 + j;
      int row = c64 * 16 + hw;
      *(u32*)&Ab[(row << 6) + ((jb ^ (row & 7)) << 3) + (c & 7)] =
          pack_bf16x2(F4C(v0, j), F4C(v1, j));
    }
  }
}

__global__ __launch_bounds__(256, 2)
void fc_mfma(const float* __restrict__ feat, const u16* __restrict__ wtf,
             const float* __restrict__ fb, const float* __restrict__ gw,
             const float* __restrict__ gb, u16* __restrict__ x0,
             float* __restrict__ sc, float* __restrict__ sh)
{
  __shared__ __align__(16) u16 Wl[256 * 64];
  __shared__ __align__(16) u16 Al[2][64 * 64];
  const int t = threadIdx.x;
  const int lane = t & 63, wave = t >> 6;
  const int n15 = lane & 15, kq = lane >> 4;
  const int d0 = blockIdx.x * 64;
  const int b0 = blockIdx.y * 8;

#pragma unroll
  for (int it = 0; it < 8; ++it) {
    int idx = t + it * 256;
    int dl = idx >> 5, jb32 = idx & 31;
    int row = (jb32 >> 3) * 64 + dl, jb = jb32 & 7;
    uint4 v = *(const uint4*)(wtf + (size_t)(d0 + dl) * 256 + jb32 * 8);
    *(uint4*)&Wl[(row << 6) + ((jb ^ (row & 7)) << 3)] = v;
  }
  fc_stage_A(feat, b0, Al[0], t);

  const int dg = d0 + wave * 16 + n15;
  const float bvn = fb[dg];
  const float gwv = gw[dg], gbv = gb[dg];

  for (int bi = 0; bi < 8; ++bi) {
    __syncthreads();
    if (bi + 1 < 8) fc_stage_A(feat, b0 + bi + 1, Al[(bi + 1) & 1], t);

    const u16* A = Al[bi & 1];
    f32x4 acc0 = {0.f, 0.f, 0.f, 0.f}, acc1 = {0.f, 0.f, 0.f, 0.f};
#pragma unroll
    for (int ks = 0; ks < 8; ++ks) {
      int js = ks * 4 + kq;
      int ra = (js >> 3) * 16 + n15;
      int rb = (js >> 3) * 64 + wave * 16 + n15;
      short8 av = *(const short8*)&A[(ra << 6) + (((js & 7) ^ (ra & 7)) << 3)];
      short8 bv = *(const short8*)&Wl[(rb << 6) + (((js & 7) ^ (rb & 7)) << 3)];
      if (ks & 1) acc1 = __builtin_amdgcn_mfma_f32_16x16x32_bf16(av, bv, acc1, 0, 0, 0);
      else        acc0 = __builtin_amdgcn_mfma_f32_16x16x32_bf16(av, bv, acc0, 0, 0, 0);
    }

    int b = b0 + bi;
    float v[4], s = 0.f, s2 = 0.f;
#pragma unroll
    for (int r = 0; r < 4; ++r) {
      v[r] = fmaxf(acc0[r] + acc1[r] + bvn, 0.f);
      s += v[r]; s2 += v[r] * v[r];
    }
    uint2 pk = {pack_bf16x2(v[0], v[1]), pack_bf16x2(v[2], v[3])};
    *(uint2*)&x0[((size_t)b * 512 + dg) * 16 + kq * 4] = pk;
    s  += __shfl_xor(s, 16, 64);  s  += __shfl_xor(s, 32, 64);
    s2 += __shfl_xor(s2, 16, 64); s2 += __shfl_xor(s2, 32, 64);
    if (kq == 0) {
      float mu = s * (1.f / 16.f);
      float var = fmaxf(s2 * (1.f / 16.f) - mu * mu, 0.f);
      float scale = gwv * rsqrtf(var + 1e-5f);
      sc[(size_t)b * 512 + dg] = scale;
      sh[(size_t)b * 512 + dg] = gbv - mu * scale;
    }
  }
}

// ---------------- deconv stages 0/1 via bf16 MFMA + fused next-GN stats ----------------
template<int STAGE>
__global__ __launch_bounds__(256, 3)
void deconv_mfma(const u16* __restrict__ x, const float* __restrict__ sc,
                 const float* __restrict__ sh, const u16* __restrict__ wt,
                 const float* __restrict__ bias, u16* __restrict__ y,
                 const float* __restrict__ gwn, const float* __restrict__ gbn,
                 float* __restrict__ osc, float* __restrict__ osh)
{
  constexpr int CI  = STAGE == 0 ? 512 : 256;
  constexpr int CO  = CI / 2;
  constexpr int H   = STAGE == 0 ? 4 : 8;
  constexpr int S2I = H * H, S2O = 4 * S2I, W2 = 2 * H;
  constexpr int WP  = H + 1;
  constexpr int XROWS = STAGE == 0 ? 100 : 81;
  constexpr int NCH = CI / 64;
  __shared__ __align__(16) u16 Wl[288 * 64];
  __shared__ __align__(16) u16 Xl[XROWS * 64];
  __shared__ float2 sbuf[2][2][16];

  const int t = threadIdx.x;
  const int lane = t & 63, wave = t >> 6;
  const int ms = wave >> 1, ns = wave & 1;
  const int n15 = lane & 15, kq = lane >> 4;

  int m0, b0;
  m0 = blockIdx.x * 32; b0 = (STAGE == 0) ? blockIdx.y * 4 : blockIdx.y;

  int xrow[2];
#pragma unroll
  for (int ni = 0; ni < 2; ++ni) {
    if constexpr (STAGE == 0) xrow[ni] = (ns * 2 + ni) * 25 + (n15 >> 2) * 5 + (n15 & 3);
    else                      xrow[ni] = (2 * (ns * 2 + ni) + (n15 >> 3)) * 9 + (n15 & 7);
  }
  const int am = ms * 16 + n15;

  for (int i = t; i < XROWS * 32; i += 256) ((u32*)Xl)[i] = 0;

  f32x4 acc[2][4];
#pragma unroll
  for (int ni = 0; ni < 2; ++ni)
#pragma unroll
    for (int c = 0; c < 4; ++c) acc[ni][c] = f32x4{0.f, 0.f, 0.f, 0.f};

  for (int ch = 0; ch < NCH; ++ch) {
    const int c0 = ch * 64;
    __syncthreads();

#pragma unroll
    for (int it = 0; it < 9; ++it) {
      int idx = t + it * 256;
      int row = idx >> 3, jb = idx & 7;
      int tap = row >> 5, ml = row & 31;
      uint4 v = *(const uint4*)(wt + ((size_t)(tap * CO + m0 + ml)) * CI + c0 + jb * 8);
      *(uint4*)&Wl[(row << 6) + ((jb ^ (row & 7)) << 3)] = v;
    }

    for (int idx = t; idx < 16 * 32; idx += 256) {
      int q = idx & 15, p = idx >> 4;
      int c = c0 + 2 * p;
      int b, ldr, gpos;
      if constexpr (STAGE == 0) {
        int img = q >> 2, iy = q & 3;
        b = b0 + img; gpos = iy * 4; ldr = img * 25 + iy * 5;
      } else {
        int iy = q >> 1, cq = q & 1;
        b = b0; gpos = iy * 8 + cq * 4; ldr = iy * 9 + cq * 4;
      }
      const u16* xp = x + ((size_t)b * CI + c) * S2I + gpos;
      uint2 q0 = *(const uint2*)xp;
      uint2 q1 = *(const uint2*)(xp + S2I);
      float s0 = sc[(size_t)b * CI + c],     h0 = sh[(size_t)b * CI + c];
      float s1 = sc[(size_t)b * CI + c + 1], h1 = sh[(size_t)b * CI + c + 1];
      int jb = p >> 2, sub = p & 3;
#pragma unroll
      for (int j = 0; j < 4; ++j) {
        int row = ldr + j;
        *(u32*)&Xl[(row << 6) + ((jb ^ (row & 7)) << 3) + sub * 2] =
            pack_bf16x2(bfel(q0, j) * s0 + h0, bfel(q1, j) * s1 + h1);
      }
    }
    __syncthreads();

#pragma unroll
    for (int s = 0; s < 2; ++s) {
      const int js = s * 4 + kq;
      short8 a[9];
#pragma unroll
      for (int tap = 0; tap < 9; ++tap) {
        int row = tap * 32 + am;
        a[tap] = *(const short8*)&Wl[(row << 6) + ((js ^ (row & 7)) << 3)];
      }
#pragma unroll
      for (int ni = 0; ni < 2; ++ni) {
        int r0 = xrow[ni], r1 = r0 + 1, r2 = r0 + WP, r3 = r0 + WP + 1;
        short8 b00 = *(const short8*)&Xl[(r0 << 6) + ((js ^ (r0 & 7)) << 3)];
        short8 b01 = *(const short8*)&Xl[(r1 << 6) + ((js ^ (r1 & 7)) << 3)];
        short8 b10 = *(const short8*)&Xl[(r2 << 6) + ((js ^ (r2 & 7)) << 3)];
        short8 b11 = *(const short8*)&Xl[(r3 << 6) + ((js ^ (r3 & 7)) << 3)];
        acc[ni][0] = __builtin_amdgcn_mfma_f32_16x16x32_bf16(a[4], b00, acc[ni][0], 0, 0, 0);
        acc[ni][1] = __builtin_amdgcn_mfma_f32_16x16x32_bf16(a[3], b00, acc[ni][1], 0, 0, 0);
        acc[ni][1] = __builtin_amdgcn_mfma_f32_16x16x32_bf16(a[5], b01, acc[ni][1], 0, 0, 0);
        acc[ni][2] = __builtin_amdgcn_mfma_f32_16x16x32_bf16(a[1], b00, acc[ni][2], 0, 0, 0);
        acc[ni][2] = __builtin_amdgcn_mfma_f32_16x16x32_bf16(a[7], b10, acc[ni][2], 0, 0, 0);
        acc[ni][3] = __builtin_amdgcn_mfma_f32_16x16x32_bf16(a[0], b00, acc[ni][3], 0, 0, 0);
        acc[ni][3] = __builtin_amdgcn_mfma_f32_16x16x32_bf16(a[2], b01, acc[ni][3], 0, 0, 0);
        acc[ni][3] = __builtin_amdgcn_mfma_f32_16x16x32_bf16(a[6], b10, acc[ni][3], 0, 0, 0);
        acc[ni][3] = __builtin_amdgcn_mfma_f32_16x16x32_bf16(a[8], b11, acc[ni][3], 0, 0, 0);
      }
    }
  }

  // ---- epilogue: bias + relu + store + fused stats for next GN ----
  float bv[4];
#pragma unroll
  for (int r = 0; r < 4; ++r) bv[r] = bias[m0 + ms * 16 + kq * 4 + r];

  float sr[4] = {0.f, 0.f, 0.f, 0.f}, sr2[4] = {0.f, 0.f, 0.f, 0.f};
#pragma unroll
  for (int ni = 0; ni < 2; ++ni) {
    int b, iy, ix;
    if constexpr (STAGE == 0) { b = b0 + ns * 2 + ni; iy = n15 >> 2; ix = n15 & 3; }
    else                      { b = b0; iy = 2 * (ns * 2 + ni) + (n15 >> 3); ix = n15 & 7; }

    float val[4][4];   // [class][r]
#pragma unroll
    for (int cl = 0; cl < 4; ++cl)
#pragma unroll
      for (int r = 0; r < 4; ++r) {
        val[cl][r] = fmaxf(acc[ni][cl][r] + bv[r], 0.f);
        sr[r] += val[cl][r]; sr2[r] += val[cl][r] * val[cl][r];
      }

    if constexpr (STAGE == 0) {
#pragma unroll
      for (int r = 0; r < 4; ++r) {
        int m = m0 + ms * 16 + kq * 4 + r;
        size_t base = ((size_t)b * CO + m) * S2O + (size_t)(2 * iy) * W2 + 2 * ix;
        *(u32*)(y + base)      = pack_bf16x2(val[0][r], val[1][r]);
        *(u32*)(y + base + W2) = pack_bf16x2(val[2][r], val[3][r]);
      }
#pragma unroll
      for (int r = 0; r < 4; ++r) {
#pragma unroll
        for (int off = 1; off <= 8; off <<= 1) {
          sr[r]  += __shfl_xor(sr[r], off, 64);
          sr2[r] += __shfl_xor(sr2[r], off, 64);
        }
      }
      if (n15 == 0) {
#pragma unroll
        for (int r = 0; r < 4; ++r) {
          int m = m0 + ms * 16 + kq * 4 + r;
          float mu = sr[r] * (1.f / 64.f);
          float var = fmaxf(sr2[r] * (1.f / 64.f) - mu * mu, 0.f);
          float scale = gwn[m] * rsqrtf(var + 1e-5f);
          osc[(size_t)b * CO + m] = scale;
          osh[(size_t)b * CO + m] = gbn[m] - mu * scale;
        }
      }
#pragma unroll
      for (int r = 0; r < 4; ++r) { sr[r] = 0.f; sr2[r] = 0.f; }
    } else {
      // x2 layout [b][256 px][128 c]
#pragma unroll
      for (int cl = 0; cl < 4; ++cl) {
        int opx = (2 * iy + (cl >> 1)) * 16 + 2 * ix + (cl & 1);
        size_t base = ((size_t)b * 256 + opx) * 128 + m0 + ms * 16 + kq * 4;
        *(u32*)(y + base)     = pack_bf16x2(val[cl][0], val[cl][1]);
        *(u32*)(y + base + 2) = pack_bf16x2(val[cl][2], val[cl][3]);
      }
    }
  }

  if constexpr (STAGE == 1) {
#pragma unroll
    for (int r = 0; r < 4; ++r) {
#pragma unroll
      for (int off = 1; off <= 8; off <<= 1) {
        sr[r]  += __shfl_xor(sr[r], off, 64);
        sr2[r] += __shfl_xor(sr2[r], off, 64);
      }
    }
    __syncthreads();
    if (n15 == 0) {
#pragma unroll
      for (int r = 0; r < 4; ++r) sbuf[ms][ns][kq * 4 + r] = float2{sr[r], sr2[r]};
    }
    __syncthreads();
    if (t < 32) {
      int msx = t >> 4, i = t & 15;
      float2 p0 = sbuf[msx][0][i], p1 = sbuf[msx][1][i];
      float s = p0.x + p1.x, s2 = p0.y + p1.y;
      float mu = s * (1.f / 256.f);
      float var = fmaxf(s2 * (1.f / 256.f) - mu * mu, 0.f);
      int m = m0 + msx * 16 + i;
      float scale = gwn[m] * rsqrtf(var + 1e-5f);
      osc[(size_t)b0 * CO + m] = scale;
      osh[(size_t)b0 * CO + m] = gbn[m] - mu * scale;
    }
  }
}

// ---------------- stage-2 deconv: X-only LDS, A-taps from global (L2-hot), B-row reuse ----------------
// x2[b][256 px][128 c] -> x3[b][64][1024] bf16 + sc3/sh3 (no affine).
// Block (m-tile 16, b); waves own 4 iy rows; per K-half: 9 global A-frags,
// 10 B ds_reads (rows shared between adjacent iy), 36 MFMAs.
#define XRD(row) (*(const short8*)&Xl[((row) << 6) + (((js ^ ((row) & 7))) << 3)])
__global__ __launch_bounds__(256, 3)
void deconv2_full(const u16* __restrict__ x, const float* __restrict__ sc,
                  const float* __restrict__ sh, const u16* __restrict__ wt,
                  const float* __restrict__ bias, u16* __restrict__ y,
                  float* __restrict__ osc, float* __restrict__ osh)
{
  __shared__ __align__(16) u16 Xl[289 * 64];   // row = iy*17 + ix (halo stays 0)
  __shared__ float sc_l[128], sh_l[128];
  __shared__ float2 sbuf[4][16];

  const int t = threadIdx.x;
  const int lane = t & 63, wv = t >> 6;
  const int n15 = lane & 15, kq = lane >> 4;
  const int m0 = blockIdx.x * 16;
  const int b  = blockIdx.y;

  if (t < 128) { sc_l[t] = sc[(size_t)b * 128 + t]; sh_l[t] = sh[(size_t)b * 128 + t]; }
  for (int i = t; i < 289 * 32; i += 256) ((u32*)Xl)[i] = 0;

  f32x4 acc[4][4];   // [nt][class]
#pragma unroll
  for (int n = 0; n < 4; ++n)
#pragma unroll
    for (int c = 0; c < 4; ++c) acc[n][c] = f32x4{0.f, 0.f, 0.f, 0.f};

  for (int ch = 0; ch < 2; ++ch) {
    const int c0 = ch * 64;
    __syncthreads();

    // stage X: 256 px x 8 c-blocks, coalesced uint4 -> b128 LDS writes
#pragma unroll
    for (int it = 0; it < 8; ++it) {
      int idx = t + it * 256;
      int px = idx >> 3, jb = idx & 7;
      uint4 q = *(const uint4*)(x + ((size_t)b * 256 + px) * 128 + c0 + jb * 8);
      int cb = c0 + jb * 8;
      float f0 = bflo(q.x) * sc_l[cb + 0] + sh_l[cb + 0];
      float f1 = bfhi(q.x) * sc_l[cb + 1] + sh_l[cb + 1];
      float f2 = bflo(q.y) * sc_l[cb + 2] + sh_l[cb + 2];
      float f3 = bfhi(q.y) * sc_l[cb + 3] + sh_l[cb + 3];
      float f4 = bflo(q.z) * sc_l[cb + 4] + sh_l[cb + 4];
      float f5 = bfhi(q.z) * sc_l[cb + 5] + sh_l[cb + 5];
      float f6 = bflo(q.w) * sc_l[cb + 6] + sh_l[cb + 6];
      float f7 = bfhi(q.w) * sc_l[cb + 7] + sh_l[cb + 7];
      uint4 o = {pack_bf16x2(f0, f1), pack_bf16x2(f2, f3),
                 pack_bf16x2(f4, f5), pack_bf16x2(f6, f7)};
      int pr = (px >> 4) * 17 + (px & 15);
      *(uint4*)&Xl[(pr << 6) + ((jb ^ (pr & 7)) << 3)] = o;
    }
    __syncthreads();

#pragma unroll
    for (int s = 0; s < 2; ++s) {
      const int js = s * 4 + kq;
      // A-taps direct from global: wt2[(tap*64+m)*128+c]; identical across all
      // 512 b-blocks -> L2-pinned. 16B aligned.
      const u16* wbase = wt + ((size_t)(m0 + n15)) * 128 + c0 + s * 32 + kq * 8;
      short8 a[9];
#pragma unroll
      for (int tap = 0; tap < 9; ++tap)
        a[tap] = *(const short8*)(wbase + (size_t)tap * 8192);

      int r = (wv * 4) * 17 + n15;
      short8 b00 = XRD(r), b01 = XRD(r + 1);
#pragma unroll
      for (int nt = 0; nt < 4; ++nt) {
        short8 b10 = XRD(r + 17), b11 = XRD(r + 18);
        acc[nt][0] = __builtin_amdgcn_mfma_f32_16x16x32_bf16(a[4], b00, acc[nt][0], 0, 0, 0);
        acc[nt][1] = __builtin_amdgcn_mfma_f32_16x16x32_bf16(a[3], b00, acc[nt][1], 0, 0, 0);
        acc[nt][1] = __builtin_amdgcn_mfma_f32_16x16x32_bf16(a[5], b01, acc[nt][1], 0, 0, 0);
        acc[nt][2] = __builtin_amdgcn_mfma_f32_16x16x32_bf16(a[1], b00, acc[nt][2], 0, 0, 0);
        acc[nt][2] = __builtin_amdgcn_mfma_f32_16x16x32_bf16(a[7], b10, acc[nt][2], 0, 0, 0);
        acc[nt][3] = __builtin_amdgcn_mfma_f32_16x16x32_bf16(a[0], b00, acc[nt][3], 0, 0, 0);
        acc[nt][3] = __builtin_amdgcn_mfma_f32_16x16x32_bf16(a[2], b01, acc[nt][3], 0, 0, 0);
        acc[nt][3] = __builtin_amdgcn_mfma_f32_16x16x32_bf16(a[6], b10, acc[nt][3], 0, 0, 0);
        acc[nt][3] = __builtin_amdgcn_mfma_f32_16x16x32_bf16(a[8], b11, acc[nt][3], 0, 0, 0);
        b00 = b10; b01 = b11; r += 17;
      }
    }
  }

  // ---- epilogue: bias + relu + store + fused stats (no affine) ----
  float bv[4];
#pragma unroll
  for (int r = 0; r < 4; ++r) bv[r] = bias[m0 + kq * 4 + r];
  float sr[4] = {0.f, 0.f, 0.f, 0.f}, sr2[4] = {0.f, 0.f, 0.f, 0.f};
#pragma unroll
  for (int nt = 0; nt < 4; ++nt) {
    int iy = wv * 4 + nt, ix = n15;
#pragma unroll
    for (int r = 0; r < 4; ++r) {
      int m = m0 + kq * 4 + r;
      float v00 = fmaxf(acc[nt][0][r] + bv[r], 0.f);
      float v01 = fmaxf(acc[nt][1][r] + bv[r], 0.f);
      float v10 = fmaxf(acc[nt][2][r] + bv[r], 0.f);
      float v11 = fmaxf(acc[nt][3][r] + bv[r], 0.f);
      size_t base = ((size_t)b * 64 + m) * 1024 + (size_t)(2 * iy) * 32 + 2 * ix;
      *(u32*)(y + base)      = pack_bf16x2(v00, v01);
      *(u32*)(y + base + 32) = pack_bf16x2(v10, v11);
      sr[r]  += v00 + v01 + v10 + v11;
      sr2[r] += v00 * v00 + v01 * v01 + v10 * v10 + v11 * v11;
    }
  }
#pragma unroll
  for (int r = 0; r < 4; ++r) {
#pragma unroll
    for (int off = 1; off <= 8; off <<= 1) {
      sr[r]  += __shfl_xor(sr[r], off, 64);
      sr2[r] += __shfl_xor(sr2[r], off, 64);
    }
  }
  __syncthreads();
  if (n15 == 0) {
#pragma unroll
    for (int r = 0; r < 4; ++r) sbuf[wv][kq * 4 + r] = float2{sr[r], sr2[r]};
  }
  __syncthreads();
  if (t < 16) {
    float s = 0.f, s2 = 0.f;
#pragma unroll
    for (int w = 0; w < 4; ++w) { s += sbuf[w][t].x; s2 += sbuf[w][t].y; }
    float mu = s * (1.f / 1024.f);
    float var = fmaxf(s2 * (1.f / 1024.f) - mu * mu, 0.f);
    float rstd = rsqrtf(var + 1e-5f);
    osc[(size_t)b * 64 + m0 + t] = rstd;
    osh[(size_t)b * 64 + m0 + t] = -mu * rstd;
  }
}

// ---------------- block reductions ----------------
DI float breduce_sum(float v, float* buf) {
#pragma unroll
  for (int off = 32; off; off >>= 1) v += __shfl_xor(v, off, 64);
  if ((threadIdx.x & 63) == 0) buf[threadIdx.x >> 6] = v;
  __syncthreads();
  float r = (buf[0] + buf[1]) + (buf[2] + buf[3]);
  __syncthreads();
  return r;
}
DI float breduce_max(float v, float* buf) {
#pragma unroll
  for (int off = 32; off; off >>= 1) v = fmaxf(v, __shfl_xor(v, off, 64));
  if ((threadIdx.x & 63) == 0) buf[threadIdx.x >> 6] = v;
  __syncthreads();
  float r = fmaxf(fmaxf(buf[0], buf[1]), fmaxf(buf[2], buf[3]));
  __syncthreads();
  return r;
}

// ---------------- head ----------------
__global__ __launch_bounds__(256)
void head_kernel(const u16* __restrict__ x3, const float* __restrict__ sc,
                 const float* __restrict__ sh, const int* __restrict__ action,
                 const float* __restrict__ hgw, const float* __restrict__ hcw,
                 float* __restrict__ out)
{
  constexpr int C = 64, S = 5, P = 1024;
  const int b = blockIdx.x, t = threadIdx.x;
  const int a = action[b];
  __shared__ float weff[S * C];
  __shared__ float rbuf[4];
  for (int j = t; j < S * C; j += 256) {
    int s = j >> 6, c = j & 63;
    weff[j] = hcw[(a * S + s) * C + c] * hgw[a * C + c];
  }
  __syncthreads();

  float L[S][4];
#pragma unroll
  for (int s = 0; s < S; ++s)
#pragma unroll
    for (int k = 0; k < 4; ++k) L[s][k] = 0.f;

  const u32* xb = (const u32*)(x3 + (size_t)b * C * P);
  for (int c = 0; c < C; ++c) {
    float scv = sc[b * C + c], shv = sh[b * C + c];
    u32 u0 = xb[c * 512 + t];
    u32 u1 = xb[c * 512 + t + 256];
    float xv[4] = {bflo(u0) * scv + shv, bfhi(u0) * scv + shv,
                   bflo(u1) * scv + shv, bfhi(u1) * scv + shv};
#pragma unroll
    for (int s = 0; s < S; ++s) {
      float wv = weff[s * C + c];
#pragma unroll
      for (int k = 0; k < 4; ++k) L[s][k] += xv[k] * wv;
    }
  }

#pragma unroll
  for (int s = 0; s < S; ++s) {
    float m = fmaxf(fmaxf(L[s][0], L[s][1]), fmaxf(L[s][2], L[s][3]));
    m = breduce_max(m, rbuf);
    float se = 0.f, sx = 0.f, sy = 0.f;
    const int pix[4] = {2 * t, 2 * t + 1, 512 + 2 * t, 512 + 2 * t + 1};
#pragma unroll
    for (int k = 0; k < 4; ++k) {
      int p = pix[k];
      float e = __expf(L[s][k] - m);
      se += e;
      sx += e * ((float)(p & 31) * (2.f / 31.f) - 1.f);
      sy += e * ((float)(p >> 5) * (2.f / 31.f) - 1.f);
    }
    se = breduce_sum(se, rbuf);
    sx = breduce_sum(sx, rbuf);
    sy = breduce_sum(sy, rbuf);
    if (t == 0) {
      out[(b * S + s) * 2 + 0] = sx / se;
      out[(b * S + s) * 2 + 1] = sy / se;
    }
  }
}

// ---------------- launcher ----------------
extern "C" void kernel_launch(void* const* d_in, const int* in_sizes, int n_in,
                              void* d_out, int out_size, void* d_ws, size_t ws_size,
                              hipStream_t stream)
{
  (void)in_sizes; (void)n_in; (void)out_size; (void)ws_size;
  const float* feat   = (const float*)d_in[0];
  const int*   action = (const int*)d_in[1];
  const float* fc_w = (const float*)d_in[3];
  const float* fc_b = (const float*)d_in[4];
  const float* gw0  = (const float*)d_in[5];
  const float* gb0  = (const float*)d_in[6];
  const float* dw0  = (const float*)d_in[7];
  const float* db0  = (const float*)d_in[8];
  const float* gw1  = (const float*)d_in[9];
  const float* gb1  = (const float*)d_in[10];
  const float* dw1  = (const float*)d_in[11];
  const float* db1  = (const float*)d_in[12];
  const float* gw2  = (const float*)d_in[13];
  const float* gb2  = (const float*)d_in[14];
  const float* dw2  = (const float*)d_in[15];
  const float* db2  = (const float*)d_in[16];
  const float* hgw  = (const float*)d_in[17];
  const float* hcw  = (const float*)d_in[19];

  float* ws = (float*)d_ws;
  u16* x0 = (u16*)(ws + OFF_REGB);
  u16* x2 = (u16*)(ws + OFF_REGB);
  u16* x1 = (u16*)(ws + OFF_REGA);
  u16* x3 = (u16*)(ws + OFF_REGA);
  u16* wt0 = (u16*)(ws + OFF_WT0);
  u16* wt1 = (u16*)(ws + OFF_WT1);
  u16* wt2 = (u16*)(ws + OFF_WT2);
  u16* wtf = (u16*)(ws + OFF_WTF);
  float* sc0 = ws + O_SC0; float* sh0 = ws + O_SH0;
  float* sc1 = ws + O_SC1; float* sh1 = ws + O_SH1;
  float* sc2 = ws + O_SC2; float* sh2 = ws + O_SH2;
  float* sc3 = ws + O_SC3; float* sh3 = ws + O_SH3;

  wtrans_all<<<1184, 256, 0, stream>>>(dw0, dw1, dw2, fc_w, wt0, wt1, wt2, wtf);
  fc_mfma<<<dim3(8, 64), 256, 0, stream>>>(feat, wtf, fc_b, gw0, gb0, x0, sc0, sh0);
  deconv_mfma<0><<<dim3(8, 128), 256, 0, stream>>>(x0, sc0, sh0, wt0, db0, x1, gw1, gb1, sc1, sh1);
  deconv_mfma<1><<<dim3(4, 512), 256, 0, stream>>>(x1, sc1, sh1, wt1, db1, x2, gw2, gb2, sc2, sh2);
  deconv2_full<<<dim3(4, 512), 256, 0, stream>>>(x2, sc2, sh2, wt2, db2, x3, sc3, sh3);
  head_kernel<<<512, 256, 0, stream>>>(x3, sc3, sh3, action, hgw, hcw, (float*)d_out);
}

// Round 10
// 266.115 us; speedup vs baseline: 1.1406x; 1.1406x over previous
//
#include <hip/hip_runtime.h>
#include <hip/hip_bf16.h>

#define DI __device__ __forceinline__
using u16 = unsigned short;
using u32 = unsigned int;

typedef short short8 __attribute__((ext_vector_type(8)));   // 8 bf16 (4 VGPRs)
typedef float f32x4 __attribute__((ext_vector_type(4)));

#define F4C(v, i) ((i) == 0 ? (v).x : (i) == 1 ? (v).y : (i) == 2 ? (v).z : (v).w)

DI float bflo(u32 u) { return __uint_as_float(u << 16); }
DI float bfhi(u32 u) { return __uint_as_float(u & 0xffff0000u); }
DI float bfel(uint2 u, int j) { u32 w = (j < 2) ? u.x : u.y; return (j & 1) ? bfhi(w) : bflo(w); }
DI u16 f2bf(float a) {
  u32 xu = __float_as_uint(a);
  return (u16)((xu + 0x7fffu + ((xu >> 16) & 1)) >> 16);
}
DI u32 pack_bf16x2(float a, float b) {
  u32 xu = __float_as_uint(a), yu = __float_as_uint(b);
  xu = (xu + 0x7fffu + ((xu >> 16) & 1)) >> 16;
  yu = (yu + 0x7fffu + ((yu >> 16) & 1)) >> 16;
  return (xu & 0xffffu) | (yu << 16);
}

// ---------------- workspace layout (float units) ----------------
static constexpr size_t OFF_REGB = 0;
static constexpr size_t OFF_REGA = 16777216;
static constexpr size_t OFF_WT0  = 33554432;
static constexpr size_t OFF_WT1  = OFF_WT0 + 1179648;
static constexpr size_t OFF_WT2  = OFF_WT1 + 294912;
static constexpr size_t OFF_WTF  = OFF_WT2 + 73728;
static constexpr size_t OFF_ST   = 35200000;
static constexpr size_t O_SC0 = OFF_ST,          O_SH0 = OFF_ST + 262144;
static constexpr size_t O_SC1 = OFF_ST + 524288, O_SH1 = OFF_ST + 655360;
static constexpr size_t O_SC2 = OFF_ST + 786432, O_SH2 = OFF_ST + 851968;
static constexpr size_t O_PSUM = OFF_ST + 1048576;   // 512*64*4 float2 = 262144 floats

// ---------------- all weight pre-transposes in one launch ----------------
__global__ __launch_bounds__(256)
void wtrans_all(const float* __restrict__ dw0, const float* __restrict__ dw1,
                const float* __restrict__ dw2, const float* __restrict__ fcw,
                u16* __restrict__ wt0, u16* __restrict__ wt1,
                u16* __restrict__ wt2, u16* __restrict__ wtf)
{
  int id = blockIdx.x * 256 + threadIdx.x;
  if (id < 131072) {                       // dw0: CO=256, CI=512
    int m = id >> 9, c = id & 511;
    const float* src = dw0 + ((size_t)m * 512 + c) * 9;
#pragma unroll
    for (int tap = 0; tap < 9; ++tap)
      wt0[((size_t)tap * 256 + m) * 512 + c] = f2bf(src[tap]);
  } else if (id < 163840) {                // dw1: CO=128, CI=256
    int j = id - 131072;
    int m = j >> 8, c = j & 255;
    const float* src = dw1 + ((size_t)m * 256 + c) * 9;
#pragma unroll
    for (int tap = 0; tap < 9; ++tap)
      wt1[((size_t)tap * 128 + m) * 256 + c] = f2bf(src[tap]);
  } else if (id < 172032) {                // dw2: CO=64, CI=128
    int j = id - 163840;
    int m = j >> 7, c = j & 127;
    const float* src = dw2 + ((size_t)m * 128 + c) * 9;
#pragma unroll
    for (int tap = 0; tap < 9; ++tap)
      wt2[((size_t)tap * 64 + m) * 128 + c] = f2bf(src[tap]);
  } else {                                 // fc: wtf[d][c]
    int j = id - 172032;
    int d = j >> 8, c = j & 255;
    wtf[j] = f2bf(fcw[c * 512 + d]);
  }
}

// ---------------- fc1 via MFMA + fused GN0 stats ----------------
DI void fc_stage_A(const float* __restrict__ feat, int b, u16* Ab, int t)
{
#pragma unroll
  for (int it = 0; it < 2; ++it) {
    int idx = t + it * 256;
    int cp = idx >> 2, hw4 = idx & 3;
    int c = cp * 2;
    const float* xp = feat + ((size_t)b * 256 + c) * 16 + hw4 * 4;
    float4 v0 = *(const float4*)xp;
    float4 v1 = *(const float4*)(xp + 16);
    int c64 = c >> 6, jb = (c & 63) >> 3;
#pragma unroll
    for (int j = 0; j < 4; ++j) {
      int hw = hw4 * 4 + j;
      int row = c64 * 16 + hw;
      *(u32*)&Ab[(row << 6) + ((jb ^ (row & 7)) << 3) + (c & 7)] =
          pack_bf16x2(F4C(v0, j), F4C(v1, j));
    }
  }
}

__global__ __launch_bounds__(256, 2)
void fc_mfma(const float* __restrict__ feat, const u16* __restrict__ wtf,
             const float* __restrict__ fb, const float* __restrict__ gw,
             const float* __restrict__ gb, u16* __restrict__ x0,
             float* __restrict__ sc, float* __restrict__ sh)
{
  __shared__ __align__(16) u16 Wl[256 * 64];
  __shared__ __align__(16) u16 Al[2][64 * 64];
  const int t = threadIdx.x;
  const int lane = t & 63, wave = t >> 6;
  const int n15 = lane & 15, kq = lane >> 4;
  const int d0 = blockIdx.x * 64;
  const int b0 = blockIdx.y * 8;

#pragma unroll
  for (int it = 0; it < 8; ++it) {
    int idx = t + it * 256;
    int dl = idx >> 5, jb32 = idx & 31;
    int row = (jb32 >> 3) * 64 + dl, jb = jb32 & 7;
    uint4 v = *(const uint4*)(wtf + (size_t)(d0 + dl) * 256 + jb32 * 8);
    *(uint4*)&Wl[(row << 6) + ((jb ^ (row & 7)) << 3)] = v;
  }
  fc_stage_A(feat, b0, Al[0], t);

  const int dg = d0 + wave * 16 + n15;
  const float bvn = fb[dg];
  const float gwv = gw[dg], gbv = gb[dg];

  for (int bi = 0; bi < 8; ++bi) {
    __syncthreads();
    if (bi + 1 < 8) fc_stage_A(feat, b0 + bi + 1, Al[(bi + 1) & 1], t);

    const u16* A = Al[bi & 1];
    f32x4 acc0 = {0.f, 0.f, 0.f, 0.f}, acc1 = {0.f, 0.f, 0.f, 0.f};
#pragma unroll
    for (int ks = 0; ks < 8; ++ks) {
      int js = ks * 4 + kq;
      int ra = (js >> 3) * 16 + n15;
      int rb = (js >> 3) * 64 + wave * 16 + n15;
      short8 av = *(const short8*)&A[(ra << 6) + (((js & 7) ^ (ra & 7)) << 3)];
      short8 bv = *(const short8*)&Wl[(rb << 6) + (((js & 7) ^ (rb & 7)) << 3)];
      if (ks & 1) acc1 = __builtin_amdgcn_mfma_f32_16x16x32_bf16(av, bv, acc1, 0, 0, 0);
      else        acc0 = __builtin_amdgcn_mfma_f32_16x16x32_bf16(av, bv, acc0, 0, 0, 0);
    }

    int b = b0 + bi;
    float v[4], s = 0.f, s2 = 0.f;
#pragma unroll
    for (int r = 0; r < 4; ++r) {
      v[r] = fmaxf(acc0[r] + acc1[r] + bvn, 0.f);
      s += v[r]; s2 += v[r] * v[r];
    }
    uint2 pk = {pack_bf16x2(v[0], v[1]), pack_bf16x2(v[2], v[3])};
    *(uint2*)&x0[((size_t)b * 512 + dg) * 16 + kq * 4] = pk;
    s  += __shfl_xor(s, 16, 64);  s  += __shfl_xor(s, 32, 64);
    s2 += __shfl_xor(s2, 16, 64); s2 += __shfl_xor(s2, 32, 64);
    if (kq == 0) {
      float mu = s * (1.f / 16.f);
      float var = fmaxf(s2 * (1.f / 16.f) - mu * mu, 0.f);
      float scale = gwv * rsqrtf(var + 1e-5f);
      sc[(size_t)b * 512 + dg] = scale;
      sh[(size_t)b * 512 + dg] = gbv - mu * scale;
    }
  }
}

// ---------------- deconv stages 0/1 via bf16 MFMA + fused next-GN stats ----------------
template<int STAGE>
__global__ __launch_bounds__(256, 3)
void deconv_mfma(const u16* __restrict__ x, const float* __restrict__ sc,
                 const float* __restrict__ sh, const u16* __restrict__ wt,
                 const float* __restrict__ bias, u16* __restrict__ y,
                 const float* __restrict__ gwn, const float* __restrict__ gbn,
                 float* __restrict__ osc, float* __restrict__ osh)
{
  constexpr int CI  = STAGE == 0 ? 512 : 256;
  constexpr int CO  = CI / 2;
  constexpr int H   = STAGE == 0 ? 4 : 8;
  constexpr int S2I = H * H, S2O = 4 * S2I, W2 = 2 * H;
  constexpr int WP  = H + 1;
  constexpr int XROWS = STAGE == 0 ? 100 : 81;
  constexpr int NCH = CI / 64;
  __shared__ __align__(16) u16 Wl[288 * 64];
  __shared__ __align__(16) u16 Xl[XROWS * 64];
  __shared__ float2 sbuf[2][2][16];

  const int t = threadIdx.x;
  const int lane = t & 63, wave = t >> 6;
  const int ms = wave >> 1, ns = wave & 1;
  const int n15 = lane & 15, kq = lane >> 4;

  int m0, b0;
  m0 = blockIdx.x * 32; b0 = (STAGE == 0) ? blockIdx.y * 4 : blockIdx.y;

  int xrow[2];
#pragma unroll
  for (int ni = 0; ni < 2; ++ni) {
    if constexpr (STAGE == 0) xrow[ni] = (ns * 2 + ni) * 25 + (n15 >> 2) * 5 + (n15 & 3);
    else                      xrow[ni] = (2 * (ns * 2 + ni) + (n15 >> 3)) * 9 + (n15 & 7);
  }
  const int am = ms * 16 + n15;

  for (int i = t; i < XROWS * 32; i += 256) ((u32*)Xl)[i] = 0;

  f32x4 acc[2][4];
#pragma unroll
  for (int ni = 0; ni < 2; ++ni)
#pragma unroll
    for (int c = 0; c < 4; ++c) acc[ni][c] = f32x4{0.f, 0.f, 0.f, 0.f};

  for (int ch = 0; ch < NCH; ++ch) {
    const int c0 = ch * 64;
    __syncthreads();

#pragma unroll
    for (int it = 0; it < 9; ++it) {
      int idx = t + it * 256;
      int row = idx >> 3, jb = idx & 7;
      int tap = row >> 5, ml = row & 31;
      uint4 v = *(const uint4*)(wt + ((size_t)(tap * CO + m0 + ml)) * CI + c0 + jb * 8);
      *(uint4*)&Wl[(row << 6) + ((jb ^ (row & 7)) << 3)] = v;
    }

    for (int idx = t; idx < 16 * 32; idx += 256) {
      int q = idx & 15, p = idx >> 4;
      int c = c0 + 2 * p;
      int b, ldr, gpos;
      if constexpr (STAGE == 0) {
        int img = q >> 2, iy = q & 3;
        b = b0 + img; gpos = iy * 4; ldr = img * 25 + iy * 5;
      } else {
        int iy = q >> 1, cq = q & 1;
        b = b0; gpos = iy * 8 + cq * 4; ldr = iy * 9 + cq * 4;
      }
      const u16* xp = x + ((size_t)b * CI + c) * S2I + gpos;
      uint2 q0 = *(const uint2*)xp;
      uint2 q1 = *(const uint2*)(xp + S2I);
      float s0 = sc[(size_t)b * CI + c],     h0 = sh[(size_t)b * CI + c];
      float s1 = sc[(size_t)b * CI + c + 1], h1 = sh[(size_t)b * CI + c + 1];
      int jb = p >> 2, sub = p & 3;
#pragma unroll
      for (int j = 0; j < 4; ++j) {
        int row = ldr + j;
        *(u32*)&Xl[(row << 6) + ((jb ^ (row & 7)) << 3) + sub * 2] =
            pack_bf16x2(bfel(q0, j) * s0 + h0, bfel(q1, j) * s1 + h1);
      }
    }
    __syncthreads();

#pragma unroll
    for (int s = 0; s < 2; ++s) {
      const int js = s * 4 + kq;
      short8 a[9];
#pragma unroll
      for (int tap = 0; tap < 9; ++tap) {
        int row = tap * 32 + am;
        a[tap] = *(const short8*)&Wl[(row << 6) + ((js ^ (row & 7)) << 3)];
      }
#pragma unroll
      for (int ni = 0; ni < 2; ++ni) {
        int r0 = xrow[ni], r1 = r0 + 1, r2 = r0 + WP, r3 = r0 + WP + 1;
        short8 b00 = *(const short8*)&Xl[(r0 << 6) + ((js ^ (r0 & 7)) << 3)];
        short8 b01 = *(const short8*)&Xl[(r1 << 6) + ((js ^ (r1 & 7)) << 3)];
        short8 b10 = *(const short8*)&Xl[(r2 << 6) + ((js ^ (r2 & 7)) << 3)];
        short8 b11 = *(const short8*)&Xl[(r3 << 6) + ((js ^ (r3 & 7)) << 3)];
        acc[ni][0] = __builtin_amdgcn_mfma_f32_16x16x32_bf16(a[4], b00, acc[ni][0], 0, 0, 0);
        acc[ni][1] = __builtin_amdgcn_mfma_f32_16x16x32_bf16(a[3], b00, acc[ni][1], 0, 0, 0);
        acc[ni][1] = __builtin_amdgcn_mfma_f32_16x16x32_bf16(a[5], b01, acc[ni][1], 0, 0, 0);
        acc[ni][2] = __builtin_amdgcn_mfma_f32_16x16x32_bf16(a[1], b00, acc[ni][2], 0, 0, 0);
        acc[ni][2] = __builtin_amdgcn_mfma_f32_16x16x32_bf16(a[7], b10, acc[ni][2], 0, 0, 0);
        acc[ni][3] = __builtin_amdgcn_mfma_f32_16x16x32_bf16(a[0], b00, acc[ni][3], 0, 0, 0);
        acc[ni][3] = __builtin_amdgcn_mfma_f32_16x16x32_bf16(a[2], b01, acc[ni][3], 0, 0, 0);
        acc[ni][3] = __builtin_amdgcn_mfma_f32_16x16x32_bf16(a[6], b10, acc[ni][3], 0, 0, 0);
        acc[ni][3] = __builtin_amdgcn_mfma_f32_16x16x32_bf16(a[8], b11, acc[ni][3], 0, 0, 0);
      }
    }
  }

  // ---- epilogue: bias + relu + store + fused stats for next GN ----
  float bv[4];
#pragma unroll
  for (int r = 0; r < 4; ++r) bv[r] = bias[m0 + ms * 16 + kq * 4 + r];

  float sr[4] = {0.f, 0.f, 0.f, 0.f}, sr2[4] = {0.f, 0.f, 0.f, 0.f};
#pragma unroll
  for (int ni = 0; ni < 2; ++ni) {
    int b, iy, ix;
    if constexpr (STAGE == 0) { b = b0 + ns * 2 + ni; iy = n15 >> 2; ix = n15 & 3; }
    else                      { b = b0; iy = 2 * (ns * 2 + ni) + (n15 >> 3); ix = n15 & 7; }

    float val[4][4];   // [class][r]
#pragma unroll
    for (int cl = 0; cl < 4; ++cl)
#pragma unroll
      for (int r = 0; r < 4; ++r) {
        val[cl][r] = fmaxf(acc[ni][cl][r] + bv[r], 0.f);
        sr[r] += val[cl][r]; sr2[r] += val[cl][r] * val[cl][r];
      }

    if constexpr (STAGE == 0) {
#pragma unroll
      for (int r = 0; r < 4; ++r) {
        int m = m0 + ms * 16 + kq * 4 + r;
        size_t base = ((size_t)b * CO + m) * S2O + (size_t)(2 * iy) * W2 + 2 * ix;
        *(u32*)(y + base)      = pack_bf16x2(val[0][r], val[1][r]);
        *(u32*)(y + base + W2) = pack_bf16x2(val[2][r], val[3][r]);
      }
#pragma unroll
      for (int r = 0; r < 4; ++r) {
#pragma unroll
        for (int off = 1; off <= 8; off <<= 1) {
          sr[r]  += __shfl_xor(sr[r], off, 64);
          sr2[r] += __shfl_xor(sr2[r], off, 64);
        }
      }
      if (n15 == 0) {
#pragma unroll
        for (int r = 0; r < 4; ++r) {
          int m = m0 + ms * 16 + kq * 4 + r;
          float mu = sr[r] * (1.f / 64.f);
          float var = fmaxf(sr2[r] * (1.f / 64.f) - mu * mu, 0.f);
          float scale = gwn[m] * rsqrtf(var + 1e-5f);
          osc[(size_t)b * CO + m] = scale;
          osh[(size_t)b * CO + m] = gbn[m] - mu * scale;
        }
      }
#pragma unroll
      for (int r = 0; r < 4; ++r) { sr[r] = 0.f; sr2[r] = 0.f; }
    } else {
      // x2 layout [b][256 px][128 c]
#pragma unroll
      for (int cl = 0; cl < 4; ++cl) {
        int opx = (2 * iy + (cl >> 1)) * 16 + 2 * ix + (cl & 1);
        size_t base = ((size_t)b * 256 + opx) * 128 + m0 + ms * 16 + kq * 4;
        *(u32*)(y + base)     = pack_bf16x2(val[cl][0], val[cl][1]);
        *(u32*)(y + base + 2) = pack_bf16x2(val[cl][2], val[cl][3]);
      }
    }
  }

  if constexpr (STAGE == 1) {
#pragma unroll
    for (int r = 0; r < 4; ++r) {
#pragma unroll
      for (int off = 1; off <= 8; off <<= 1) {
        sr[r]  += __shfl_xor(sr[r], off, 64);
        sr2[r] += __shfl_xor(sr2[r], off, 64);
      }
    }
    __syncthreads();
    if (n15 == 0) {
#pragma unroll
      for (int r = 0; r < 4; ++r) sbuf[ms][ns][kq * 4 + r] = float2{sr[r], sr2[r]};
    }
    __syncthreads();
    if (t < 32) {
      int msx = t >> 4, i = t & 15;
      float2 p0 = sbuf[msx][0][i], p1 = sbuf[msx][1][i];
      float s = p0.x + p1.x, s2 = p0.y + p1.y;
      float mu = s * (1.f / 256.f);
      float var = fmaxf(s2 * (1.f / 256.f) - mu * mu, 0.f);
      int m = m0 + msx * 16 + i;
      float scale = gwn[m] * rsqrtf(var + 1e-5f);
      osc[(size_t)b0 * CO + m] = scale;
      osh[(size_t)b0 * CO + m] = gbn[m] - mu * scale;
    }
  }
}

// ---------------- stage-2 deconv: round-7 shape (W+X LDS, quarter image), new layout ----------------
// x2[b][256 px][128 c] -> x3[b][64][1024] bf16; per-block stat partials -> psum[b][m][qz].
// Block: (m-half 32, qz quarter, b); 4 waves = 2 m-slots x 2 n-slots; adjacent
// n-tiles share B rows -> 14 ds_reads per 18 MFMAs.
#define XRD(row) (*(const short8*)&Xl[((row) << 6) + (((js ^ ((row) & 7))) << 3)])
__global__ __launch_bounds__(256, 3)
void deconv2_q(const u16* __restrict__ x, const float* __restrict__ sc,
               const float* __restrict__ sh, const u16* __restrict__ wt,
               const float* __restrict__ bias, u16* __restrict__ y,
               float2* __restrict__ psum)
{
  __shared__ __align__(16) u16 Wl[288 * 64];
  __shared__ __align__(16) u16 Xl[85 * 64];   // row = rl*17 + ix, rl 0..4 (halo stays 0)
  __shared__ float sc_l[128], sh_l[128];
  __shared__ float2 sbuf[2][2][16];

  const int t = threadIdx.x;
  const int lane = t & 63, wave = t >> 6;
  const int ms = wave >> 1, ns = wave & 1;
  const int n15 = lane & 15, kq = lane >> 4;
  const int m0 = (blockIdx.x & 1) * 32;
  const int qz = blockIdx.x >> 1;
  const int b  = blockIdx.y;

  if (t < 128) { sc_l[t] = sc[(size_t)b * 128 + t]; sh_l[t] = sh[(size_t)b * 128 + t]; }
  for (int i = t; i < 85 * 32; i += 256) ((u32*)Xl)[i] = 0;

  const int am = ms * 16 + n15;
  const int xr0 = (ns * 2) * 17 + n15;

  f32x4 acc[2][4];
#pragma unroll
  for (int ni = 0; ni < 2; ++ni)
#pragma unroll
    for (int c = 0; c < 4; ++c) acc[ni][c] = f32x4{0.f, 0.f, 0.f, 0.f};

  const int NPX = (qz < 3) ? 80 : 64;
  for (int ch = 0; ch < 2; ++ch) {
    const int c0 = ch * 64;
    __syncthreads();

    // ---- stage W: 288 rows (tap*32+ml) x 8 blocks ----
#pragma unroll
    for (int it = 0; it < 9; ++it) {
      int idx = t + it * 256;
      int row = idx >> 3, jb = idx & 7;
      int tap = row >> 5, ml = row & 31;
      uint4 v = *(const uint4*)(wt + ((size_t)(tap * 64 + m0 + ml)) * 128 + c0 + jb * 8);
      *(uint4*)&Wl[(row << 6) + ((jb ^ (row & 7)) << 3)] = v;
    }

    // ---- stage X: NPX px x 8 c-blocks, coalesced uint4 -> swizzled b128 ----
    for (int idx = t; idx < NPX * 8; idx += 256) {
      int pxl = idx >> 3, jb = idx & 7;
      int rl = pxl >> 4, ix = pxl & 15;
      int gpx = (4 * qz + rl) * 16 + ix;
      uint4 q = *(const uint4*)(x + ((size_t)b * 256 + gpx) * 128 + c0 + jb * 8);
      int cb = c0 + jb * 8;
      float f0 = bflo(q.x) * sc_l[cb + 0] + sh_l[cb + 0];
      float f1 = bfhi(q.x) * sc_l[cb + 1] + sh_l[cb + 1];
      float f2 = bflo(q.y) * sc_l[cb + 2] + sh_l[cb + 2];
      float f3 = bfhi(q.y) * sc_l[cb + 3] + sh_l[cb + 3];
      float f4 = bflo(q.z) * sc_l[cb + 4] + sh_l[cb + 4];
      float f5 = bfhi(q.z) * sc_l[cb + 5] + sh_l[cb + 5];
      float f6 = bflo(q.w) * sc_l[cb + 6] + sh_l[cb + 6];
      float f7 = bfhi(q.w) * sc_l[cb + 7] + sh_l[cb + 7];
      uint4 o = {pack_bf16x2(f0, f1), pack_bf16x2(f2, f3),
                 pack_bf16x2(f4, f5), pack_bf16x2(f6, f7)};
      int row = rl * 17 + ix;
      *(uint4*)&Xl[(row << 6) + ((jb ^ (row & 7)) << 3)] = o;
    }
    __syncthreads();

#pragma unroll
    for (int s = 0; s < 2; ++s) {
      const int js = s * 4 + kq;
      short8 a[9];
#pragma unroll
      for (int tap = 0; tap < 9; ++tap) {
        int row = tap * 32 + am;
        a[tap] = *(const short8*)&Wl[(row << 6) + ((js ^ (row & 7)) << 3)];
      }
      // 6 B rows shared across the wave's 2 adjacent n-tiles
      short8 B0 = XRD(xr0),      B1 = XRD(xr0 + 1);
      short8 B2 = XRD(xr0 + 17), B3 = XRD(xr0 + 18);
      short8 B4 = XRD(xr0 + 34), B5 = XRD(xr0 + 35);
#pragma unroll
      for (int ni = 0; ni < 2; ++ni) {
        short8 b00 = ni ? B2 : B0, b01 = ni ? B3 : B1;
        short8 b10 = ni ? B4 : B2, b11 = ni ? B5 : B3;
        acc[ni][0] = __builtin_amdgcn_mfma_f32_16x16x32_bf16(a[4], b00, acc[ni][0], 0, 0, 0);
        acc[ni][1] = __builtin_amdgcn_mfma_f32_16x16x32_bf16(a[3], b00, acc[ni][1], 0, 0, 0);
        acc[ni][1] = __builtin_amdgcn_mfma_f32_16x16x32_bf16(a[5], b01, acc[ni][1], 0, 0, 0);
        acc[ni][2] = __builtin_amdgcn_mfma_f32_16x16x32_bf16(a[1], b00, acc[ni][2], 0, 0, 0);
        acc[ni][2] = __builtin_amdgcn_mfma_f32_16x16x32_bf16(a[7], b10, acc[ni][2], 0, 0, 0);
        acc[ni][3] = __builtin_amdgcn_mfma_f32_16x16x32_bf16(a[0], b00, acc[ni][3], 0, 0, 0);
        acc[ni][3] = __builtin_amdgcn_mfma_f32_16x16x32_bf16(a[2], b01, acc[ni][3], 0, 0, 0);
        acc[ni][3] = __builtin_amdgcn_mfma_f32_16x16x32_bf16(a[6], b10, acc[ni][3], 0, 0, 0);
        acc[ni][3] = __builtin_amdgcn_mfma_f32_16x16x32_bf16(a[8], b11, acc[ni][3], 0, 0, 0);
      }
    }
  }

  // ---- epilogue: bias + relu + store + stat partials ----
  float bv[4];
#pragma unroll
  for (int r = 0; r < 4; ++r) bv[r] = bias[m0 + ms * 16 + kq * 4 + r];
  float sr[4] = {0.f, 0.f, 0.f, 0.f}, sr2[4] = {0.f, 0.f, 0.f, 0.f};
#pragma unroll
  for (int ni = 0; ni < 2; ++ni) {
    int iy = 4 * qz + ns * 2 + ni, ix = n15;
#pragma unroll
    for (int r = 0; r < 4; ++r) {
      int m = m0 + ms * 16 + kq * 4 + r;
      float v00 = fmaxf(acc[ni][0][r] + bv[r], 0.f);
      float v01 = fmaxf(acc[ni][1][r] + bv[r], 0.f);
      float v10 = fmaxf(acc[ni][2][r] + bv[r], 0.f);
      float v11 = fmaxf(acc[ni][3][r] + bv[r], 0.f);
      size_t base = ((size_t)b * 64 + m) * 1024 + (size_t)(2 * iy) * 32 + 2 * ix;
      *(u32*)(y + base)      = pack_bf16x2(v00, v01);
      *(u32*)(y + base + 32) = pack_bf16x2(v10, v11);
      sr[r]  += v00 + v01 + v10 + v11;
      sr2[r] += v00 * v00 + v01 * v01 + v10 * v10 + v11 * v11;
    }
  }
#pragma unroll
  for (int r = 0; r < 4; ++r) {
#pragma unroll
    for (int off = 1; off <= 8; off <<= 1) {
      sr[r]  += __shfl_xor(sr[r], off, 64);
      sr2[r] += __shfl_xor(sr2[r], off, 64);
    }
  }
  __syncthreads();
  if (n15 == 0) {
#pragma unroll
    for (int r = 0; r < 4; ++r) sbuf[ms][ns][kq * 4 + r] = float2{sr[r], sr2[r]};
  }
  __syncthreads();
  if (t < 32) {
    int msx = t >> 4, i = t & 15;
    float2 p0 = sbuf[msx][0][i], p1 = sbuf[msx][1][i];
    int m = m0 + msx * 16 + i;
    psum[((size_t)b * 64 + m) * 4 + qz] = float2{p0.x + p1.x, p0.y + p1.y};
  }
}

// ---------------- block reductions ----------------
DI float breduce_sum(float v, float* buf) {
#pragma unroll
  for (int off = 32; off; off >>= 1) v += __shfl_xor(v, off, 64);
  if ((threadIdx.x & 63) == 0) buf[threadIdx.x >> 6] = v;
  __syncthreads();
  float r = (buf[0] + buf[1]) + (buf[2] + buf[3]);
  __syncthreads();
  return r;
}
DI float breduce_max(float v, float* buf) {
#pragma unroll
  for (int off = 32; off; off >>= 1) v = fmaxf(v, __shfl_xor(v, off, 64));
  if ((threadIdx.x & 63) == 0) buf[threadIdx.x >> 6] = v;
  __syncthreads();
  float r = fmaxf(fmaxf(buf[0], buf[1]), fmaxf(buf[2], buf[3]));
  __syncthreads();
  return r;
}

// ---------------- head: fold stat partials -> norm -> 1x1 conv -> spatial softmax ----------------
__global__ __launch_bounds__(256)
void head_kernel(const u16* __restrict__ x3, const float2* __restrict__ psum,
                 const int* __restrict__ action, const float* __restrict__ hgw,
                 const float* __restrict__ hcw, float* __restrict__ out)
{
  constexpr int C = 64, S = 5, P = 1024;
  const int b = blockIdx.x, t = threadIdx.x;
  const int a = action[b];
  __shared__ float weff[S * C];
  __shared__ float sc_l[C], sh_l[C];
  __shared__ float rbuf[4];
  if (t < C) {
    float s = 0.f, s2 = 0.f;
#pragma unroll
    for (int qz = 0; qz < 4; ++qz) {
      float2 p = psum[((size_t)b * C + t) * 4 + qz];
      s += p.x; s2 += p.y;
    }
    float mu = s * (1.f / 1024.f);
    float var = fmaxf(s2 * (1.f / 1024.f) - mu * mu, 0.f);
    float rstd = rsqrtf(var + 1e-5f);
    sc_l[t] = rstd; sh_l[t] = -mu * rstd;
  }
  for (int j = t; j < S * C; j += 256) {
    int s = j >> 6, c = j & 63;
    weff[j] = hcw[(a * S + s) * C + c] * hgw[a * C + c];
  }
  __syncthreads();

  float L[S][4];
#pragma unroll
  for (int s = 0; s < S; ++s)
#pragma unroll
    for (int k = 0; k < 4; ++k) L[s][k] = 0.f;

  const u32* xb = (const u32*)(x3 + (size_t)b * C * P);
  for (int c = 0; c < C; ++c) {
    float scv = sc_l[c], shv = sh_l[c];
    u32 u0 = xb[c * 512 + t];
    u32 u1 = xb[c * 512 + t + 256];
    float xv[4] = {bflo(u0) * scv + shv, bfhi(u0) * scv + shv,
                   bflo(u1) * scv + shv, bfhi(u1) * scv + shv};
#pragma unroll
    for (int s = 0; s < S; ++s) {
      float wv = weff[s * C + c];
#pragma unroll
      for (int k = 0; k < 4; ++k) L[s][k] += xv[k] * wv;
    }
  }

#pragma unroll
  for (int s = 0; s < S; ++s) {
    float m = fmaxf(fmaxf(L[s][0], L[s][1]), fmaxf(L[s][2], L[s][3]));
    m = breduce_max(m, rbuf);
    float se = 0.f, sx = 0.f, sy = 0.f;
    const int pix[4] = {2 * t, 2 * t + 1, 512 + 2 * t, 512 + 2 * t + 1};
#pragma unroll
    for (int k = 0; k < 4; ++k) {
      int p = pix[k];
      float e = __expf(L[s][k] - m);
      se += e;
      sx += e * ((float)(p & 31) * (2.f / 31.f) - 1.f);
      sy += e * ((float)(p >> 5) * (2.f / 31.f) - 1.f);
    }
    se = breduce_sum(se, rbuf);
    sx = breduce_sum(sx, rbuf);
    sy = breduce_sum(sy, rbuf);
    if (t == 0) {
      out[(b * S + s) * 2 + 0] = sx / se;
      out[(b * S + s) * 2 + 1] = sy / se;
    }
  }
}

// ---------------- launcher ----------------
extern "C" void kernel_launch(void* const* d_in, const int* in_sizes, int n_in,
                              void* d_out, int out_size, void* d_ws, size_t ws_size,
                              hipStream_t stream)
{
  (void)in_sizes; (void)n_in; (void)out_size; (void)ws_size;
  const float* feat   = (const float*)d_in[0];
  const int*   action = (const int*)d_in[1];
  const float* fc_w = (const float*)d_in[3];
  const float* fc_b = (const float*)d_in[4];
  const float* gw0  = (const float*)d_in[5];
  const float* gb0  = (const float*)d_in[6];
  const float* dw0  = (const float*)d_in[7];
  const float* db0  = (const float*)d_in[8];
  const float* gw1  = (const float*)d_in[9];
  const float* gb1  = (const float*)d_in[10];
  const float* dw1  = (const float*)d_in[11];
  const float* db1  = (const float*)d_in[12];
  const float* gw2  = (const float*)d_in[13];
  const float* gb2  = (const float*)d_in[14];
  const float* dw2  = (const float*)d_in[15];
  const float* db2  = (const float*)d_in[16];
  const float* hgw  = (const float*)d_in[17];
  const float* hcw  = (const float*)d_in[19];

  float* ws = (float*)d_ws;
  u16* x0 = (u16*)(ws + OFF_REGB);
  u16* x2 = (u16*)(ws + OFF_REGB);
  u16* x1 = (u16*)(ws + OFF_REGA);
  u16* x3 = (u16*)(ws + OFF_REGA);
  u16* wt0 = (u16*)(ws + OFF_WT0);
  u16* wt1 = (u16*)(ws + OFF_WT1);
  u16* wt2 = (u16*)(ws + OFF_WT2);
  u16* wtf = (u16*)(ws + OFF_WTF);
  float* sc0 = ws + O_SC0; float* sh0 = ws + O_SH0;
  float* sc1 = ws + O_SC1; float* sh1 = ws + O_SH1;
  float* sc2 = ws + O_SC2; float* sh2 = ws + O_SH2;
  float2* psum = (float2*)(ws + O_PSUM);

  wtrans_all<<<1184, 256, 0, stream>>>(dw0, dw1, dw2, fc_w, wt0, wt1, wt2, wtf);
  fc_mfma<<<dim3(8, 64), 256, 0, stream>>>(feat, wtf, fc_b, gw0, gb0, x0, sc0, sh0);
  deconv_mfma<0><<<dim3(8, 128), 256, 0, stream>>>(x0, sc0, sh0, wt0, db0, x1, gw1, gb1, sc1, sh1);
  deconv_mfma<1><<<dim3(4, 512), 256, 0, stream>>>(x1, sc1, sh1, wt1, db1, x2, gw2, gb2, sc2, sh2);
  deconv2_q<<<dim3(8, 512), 256, 0, stream>>>(x2, sc2, sh2, wt2, db2, x3, psum);
  head_kernel<<<512, 256, 0, stream>>>(x3, psum, action, hgw, hcw, (float*)d_out);
}